// Round 1
// baseline (2861.364 us; speedup 1.0000x reference)
//
#include <hip/hip_runtime.h>

// GINE 2-layer GNN: N=50000 nodes, E=800000 edges, d=128 everywhere, f32.
// Per layer: agg[dst] += relu(h[src] + w_e*We + be)  (scatter over edges)
//            h' = (h + agg) @ W + b                  (dense GEMM, relu after L1)
//
// Baseline structure (round 0):
//   - edge_msg: 32 lanes per edge, float4 per lane, hardware f32 atomics.
//   - gemm_add_bias: 32 rows/block, W staged in LDS in 2 halves (32KB),
//     A-tile (x+agg) in LDS, 4x4 register tile per thread.
//   - agg in d_ws (zeroed via hipMemsetAsync, capture-safe);
//     intermediate h lives in d_out (in-place GEMM is safe: each block
//     reads only its own rows into LDS before writing them).

constexpr int NN = 50000;
constexpr int NE = 800000;
constexpr int D  = 128;
constexpr int RPB = 32;   // rows per block in the GEMM

__global__ __launch_bounds__(256) void edge_msg(
    const float* __restrict__ h,
    const int*   __restrict__ srcs,
    const int*   __restrict__ dsts,
    const float* __restrict__ ew,
    const float* __restrict__ We,
    const float* __restrict__ be,
    float*       __restrict__ agg)
{
    int tid = blockIdx.x * blockDim.x + threadIdx.x;
    int e = tid >> 5;               // 32 lanes per edge
    if (e >= NE) return;
    int d4 = (tid & 31) << 2;       // float4 chunk within the 128-dim row

    int   s  = srcs[e];
    int   dd = dsts[e];
    float w  = ew[e];

    float4 xv = *(const float4*)(h  + (size_t)s * D + d4);
    float4 wv = *(const float4*)(We + d4);
    float4 bv = *(const float4*)(be + d4);

    float4 m;
    m.x = fmaxf(0.f, xv.x + fmaf(w, wv.x, bv.x));
    m.y = fmaxf(0.f, xv.y + fmaf(w, wv.y, bv.y));
    m.z = fmaxf(0.f, xv.z + fmaf(w, wv.z, bv.z));
    m.w = fmaxf(0.f, xv.w + fmaf(w, wv.w, bv.w));

    float* a = agg + (size_t)dd * D + d4;
    unsafeAtomicAdd(a + 0, m.x);    // -> global_atomic_add_f32 (no CAS loop)
    unsafeAtomicAdd(a + 1, m.y);
    unsafeAtomicAdd(a + 2, m.z);
    unsafeAtomicAdd(a + 3, m.w);
}

// out[row][c] = (relu?) ( sum_k (A1[row][k]+A2[row][k]) * W[k][c] + bias[c] )
__global__ __launch_bounds__(256) void gemm_add_bias(
    const float* __restrict__ A1,
    const float* __restrict__ A2,
    const float* __restrict__ W,
    const float* __restrict__ bias,
    float*       __restrict__ out,
    int relu)
{
    __shared__ float Ws[64 * D];        // half of W at a time: 32 KB
    __shared__ float As[RPB][D + 4];    // +4 pad keeps float4 alignment, breaks stride

    const int t    = threadIdx.x;
    const int row0 = blockIdx.x * RPB;

    // Stage A-tile = A1 + A2 for this block's rows (must complete before any
    // write to `out` — enables in-place use where out aliases A1).
    for (int i = t; i < RPB * (D / 4); i += 256) {
        int r   = i >> 5;
        int c4  = (i & 31) << 2;
        int row = row0 + r;
        float4 v = make_float4(0.f, 0.f, 0.f, 0.f);
        if (row < NN) {
            float4 v1 = *(const float4*)(A1 + (size_t)row * D + c4);
            float4 v2 = *(const float4*)(A2 + (size_t)row * D + c4);
            v = make_float4(v1.x + v2.x, v1.y + v2.y, v1.z + v2.z, v1.w + v2.w);
        }
        *(float4*)&As[r][c4] = v;
    }

    const int tx = t & 31;   // 32 column groups of 4
    const int ty = t >> 5;   // 8 row groups of 4
    float acc[4][4] = {};

    for (int half = 0; half < 2; ++half) {
        __syncthreads();     // also covers the A-tile stage on first pass
        for (int i = t * 4; i < 64 * D; i += 256 * 4) {
            *(float4*)&Ws[i] = *(const float4*)&W[half * 64 * D + i];
        }
        __syncthreads();

        for (int k0 = 0; k0 < 64; k0 += 4) {
            float4 a[4];
            #pragma unroll
            for (int i = 0; i < 4; ++i)
                a[i] = *(const float4*)&As[ty * 4 + i][half * 64 + k0];

            #pragma unroll
            for (int kk = 0; kk < 4; ++kk) {
                float4 wv = *(const float4*)&Ws[(k0 + kk) * D + tx * 4];
                #pragma unroll
                for (int i = 0; i < 4; ++i) {
                    float av = (kk == 0) ? a[i].x :
                               (kk == 1) ? a[i].y :
                               (kk == 2) ? a[i].z : a[i].w;
                    acc[i][0] = fmaf(av, wv.x, acc[i][0]);
                    acc[i][1] = fmaf(av, wv.y, acc[i][1]);
                    acc[i][2] = fmaf(av, wv.z, acc[i][2]);
                    acc[i][3] = fmaf(av, wv.w, acc[i][3]);
                }
            }
        }
    }

    float4 bv = *(const float4*)(bias + tx * 4);
    #pragma unroll
    for (int i = 0; i < 4; ++i) {
        int row = row0 + ty * 4 + i;
        if (row < NN) {
            float4 o = make_float4(acc[i][0] + bv.x, acc[i][1] + bv.y,
                                   acc[i][2] + bv.z, acc[i][3] + bv.w);
            if (relu) {
                o.x = fmaxf(0.f, o.x); o.y = fmaxf(0.f, o.y);
                o.z = fmaxf(0.f, o.z); o.w = fmaxf(0.f, o.w);
            }
            *(float4*)(out + (size_t)row * D + tx * 4) = o;
        }
    }
}

extern "C" void kernel_launch(void* const* d_in, const int* in_sizes, int n_in,
                              void* d_out, int out_size, void* d_ws, size_t ws_size,
                              hipStream_t stream)
{
    const float* x   = (const float*)d_in[0];
    const int*   ei  = (const int*)  d_in[1];   // [2, E] int32
    const float* ew  = (const float*)d_in[2];   // [E, 1]
    const float* We1 = (const float*)d_in[3];
    const float* be1 = (const float*)d_in[4];
    const float* W1  = (const float*)d_in[5];
    const float* b1  = (const float*)d_in[6];
    const float* We2 = (const float*)d_in[7];
    const float* be2 = (const float*)d_in[8];
    const float* W2  = (const float*)d_in[9];
    const float* b2  = (const float*)d_in[10];

    float* out = (float*)d_out;          // also holds intermediate h
    float* agg = (float*)d_ws;           // [NN, D] accumulator (25.6 MB)

    const int* src = ei;
    const int* dst = ei + NE;

    const size_t aggBytes = (size_t)NN * D * sizeof(float);
    dim3 eg((unsigned)((NE * 32 + 255) / 256));          // 100000 blocks
    dim3 gg((unsigned)((NN + RPB - 1) / RPB));           // 1563 blocks

    // ---- layer 1 ----
    hipMemsetAsync(agg, 0, aggBytes, stream);
    edge_msg<<<eg, 256, 0, stream>>>(x, src, dst, ew, We1, be1, agg);
    gemm_add_bias<<<gg, 256, 0, stream>>>(x, agg, W1, b1, out, 1);

    // ---- layer 2 ----
    hipMemsetAsync(agg, 0, aggBytes, stream);
    edge_msg<<<eg, 256, 0, stream>>>(out, src, dst, ew, We2, be2, agg);
    gemm_add_bias<<<gg, 256, 0, stream>>>(out, agg, W2, b2, out, 0);
}

// Round 2
// 449.387 us; speedup vs baseline: 6.3673x; 6.3673x over previous
//
#include <hip/hip_runtime.h>

// GINE 2-layer GNN: N=50000 nodes, E=800000 edges, d=128, f32.
// Round 2: replace 102.4M f32 scatter-atomics (was 2x1342us, WRITE_SIZE 1.6GB
// per layer) with a device-built dst-CSR (built ONCE, reused by both layers)
// + gather-style aggregation (zero f32 atomics, coalesced writes).
//
// Pipeline per launch:
//   memset(deg,cur) -> count_deg -> scan_deg (1 block) -> scatter_edges
//   layer1: aggregate(x)  -> gemm(x+agg  @ W1 + b1, relu) -> out
//   layer2: aggregate(out)-> gemm(out+agg @ W2 + b2)      -> out

constexpr int NN = 50000;
constexpr int NE = 800000;
constexpr int D  = 128;
constexpr int RPB = 32;   // rows per block in the GEMM

// ---------------- CSR build ----------------

__global__ __launch_bounds__(256) void count_deg(
    const int* __restrict__ dst, int* __restrict__ deg)
{
    int e = blockIdx.x * 256 + threadIdx.x;
    if (e < NE) atomicAdd(&deg[dst[e]], 1);
}

// one block, 1024 threads: exclusive scan of deg[0..NN) -> off[0..NN]
__global__ __launch_bounds__(1024) void scan_deg(
    const int* __restrict__ deg, int* __restrict__ off)
{
    __shared__ int s[1024];
    const int T = 1024;
    int t = threadIdx.x;
    int per = (NN + T - 1) / T;             // 49
    int beg = t * per;
    int end = beg + per; if (end > NN) end = NN;

    int sum = 0;
    for (int i = beg; i < end; ++i) sum += deg[i];
    s[t] = sum;
    __syncthreads();
    for (int d = 1; d < T; d <<= 1) {
        int v = 0;
        if (t >= d) v = s[t - d];
        __syncthreads();
        if (t >= d) s[t] += v;
        __syncthreads();
    }
    int run = (t == 0) ? 0 : s[t - 1];
    for (int i = beg; i < end; ++i) { off[i] = run; run += deg[i]; }
    if (t == T - 1) off[NN] = run;          // == NE
}

__global__ __launch_bounds__(256) void scatter_edges(
    const int*   __restrict__ src,
    const int*   __restrict__ dst,
    const float* __restrict__ ew,
    const int*   __restrict__ off,
    int*         __restrict__ cur,
    int*         __restrict__ esrc,
    float*       __restrict__ ewt)
{
    int e = blockIdx.x * 256 + threadIdx.x;
    if (e >= NE) return;
    int d = dst[e];
    int pos = off[d] + atomicAdd(&cur[d], 1);
    esrc[pos] = src[e];
    ewt[pos]  = ew[e];
}

// ---------------- per-layer aggregate (gather, no atomics) ----------------
// 32 lanes per node, float4 per lane; 1-edge index prefetch to overlap the
// dependent h[src] gather with the next index load.

__global__ __launch_bounds__(256) void aggregate(
    const float* __restrict__ h,
    const int*   __restrict__ off,
    const int*   __restrict__ esrc,
    const float* __restrict__ ewt,
    const float* __restrict__ We,
    const float* __restrict__ be,
    float*       __restrict__ agg)
{
    int tid = blockIdx.x * 256 + threadIdx.x;
    int n = tid >> 5;
    if (n >= NN) return;
    int d4 = (tid & 31) << 2;

    float4 wv = *(const float4*)(We + d4);
    float4 bv = *(const float4*)(be + d4);

    int e0 = off[n], e1 = off[n + 1];
    float4 acc = make_float4(0.f, 0.f, 0.f, 0.f);

    int   s_n = 0; float w_n = 0.f;
    if (e0 < e1) { s_n = esrc[e0]; w_n = ewt[e0]; }
    for (int e = e0; e < e1; ) {
        int   s = s_n;
        float w = w_n;
        ++e;
        if (e < e1) { s_n = esrc[e]; w_n = ewt[e]; }
        float4 xv = *(const float4*)(h + (size_t)s * D + d4);
        acc.x += fmaxf(0.f, xv.x + fmaf(w, wv.x, bv.x));
        acc.y += fmaxf(0.f, xv.y + fmaf(w, wv.y, bv.y));
        acc.z += fmaxf(0.f, xv.z + fmaf(w, wv.z, bv.z));
        acc.w += fmaxf(0.f, xv.w + fmaf(w, wv.w, bv.w));
    }
    *(float4*)(agg + (size_t)n * D + d4) = acc;
}

// ---------------- GEMM: out = (relu?)((A1+A2) @ W + bias) ----------------

__global__ __launch_bounds__(256) void gemm_add_bias(
    const float* __restrict__ A1,
    const float* __restrict__ A2,
    const float* __restrict__ W,
    const float* __restrict__ bias,
    float*       __restrict__ out,
    int relu)
{
    __shared__ float Ws[64 * D];        // half of W at a time: 32 KB
    __shared__ float As[RPB][D + 4];

    const int t    = threadIdx.x;
    const int row0 = blockIdx.x * RPB;

    for (int i = t; i < RPB * (D / 4); i += 256) {
        int r   = i >> 5;
        int c4  = (i & 31) << 2;
        int row = row0 + r;
        float4 v = make_float4(0.f, 0.f, 0.f, 0.f);
        if (row < NN) {
            float4 v1 = *(const float4*)(A1 + (size_t)row * D + c4);
            float4 v2 = *(const float4*)(A2 + (size_t)row * D + c4);
            v = make_float4(v1.x + v2.x, v1.y + v2.y, v1.z + v2.z, v1.w + v2.w);
        }
        *(float4*)&As[r][c4] = v;
    }

    const int tx = t & 31;
    const int ty = t >> 5;
    float acc[4][4] = {};

    for (int half = 0; half < 2; ++half) {
        __syncthreads();
        for (int i = t * 4; i < 64 * D; i += 256 * 4) {
            *(float4*)&Ws[i] = *(const float4*)&W[half * 64 * D + i];
        }
        __syncthreads();

        for (int k0 = 0; k0 < 64; k0 += 4) {
            float4 a[4];
            #pragma unroll
            for (int i = 0; i < 4; ++i)
                a[i] = *(const float4*)&As[ty * 4 + i][half * 64 + k0];

            #pragma unroll
            for (int kk = 0; kk < 4; ++kk) {
                float4 wv = *(const float4*)&Ws[(k0 + kk) * D + tx * 4];
                #pragma unroll
                for (int i = 0; i < 4; ++i) {
                    float av = (kk == 0) ? a[i].x :
                               (kk == 1) ? a[i].y :
                               (kk == 2) ? a[i].z : a[i].w;
                    acc[i][0] = fmaf(av, wv.x, acc[i][0]);
                    acc[i][1] = fmaf(av, wv.y, acc[i][1]);
                    acc[i][2] = fmaf(av, wv.z, acc[i][2]);
                    acc[i][3] = fmaf(av, wv.w, acc[i][3]);
                }
            }
        }
    }

    float4 bv = *(const float4*)(bias + tx * 4);
    #pragma unroll
    for (int i = 0; i < 4; ++i) {
        int row = row0 + ty * 4 + i;
        if (row < NN) {
            float4 o = make_float4(acc[i][0] + bv.x, acc[i][1] + bv.y,
                                   acc[i][2] + bv.z, acc[i][3] + bv.w);
            if (relu) {
                o.x = fmaxf(0.f, o.x); o.y = fmaxf(0.f, o.y);
                o.z = fmaxf(0.f, o.z); o.w = fmaxf(0.f, o.w);
            }
            *(float4*)(out + (size_t)row * D + tx * 4) = o;
        }
    }
}

extern "C" void kernel_launch(void* const* d_in, const int* in_sizes, int n_in,
                              void* d_out, int out_size, void* d_ws, size_t ws_size,
                              hipStream_t stream)
{
    const float* x   = (const float*)d_in[0];
    const int*   ei  = (const int*)  d_in[1];   // [2, E] int32
    const float* ew  = (const float*)d_in[2];   // [E, 1]
    const float* We1 = (const float*)d_in[3];
    const float* be1 = (const float*)d_in[4];
    const float* W1  = (const float*)d_in[5];
    const float* b1  = (const float*)d_in[6];
    const float* We2 = (const float*)d_in[7];
    const float* be2 = (const float*)d_in[8];
    const float* W2  = (const float*)d_in[9];
    const float* b2  = (const float*)d_in[10];

    float* out = (float*)d_out;          // also holds intermediate h

    // workspace layout
    int*   deg  = (int*)d_ws;                    // NN
    int*   off  = deg + NN;                      // NN+1
    int*   cur  = off + NN + 1;                  // NN
    int*   esrc = cur + NN + 1;                  // NE (keep 8B align slack)
    float* ewt  = (float*)(esrc + NE);           // NE
    float* agg  = ewt + NE;                      // NN*D

    const int* src = ei;
    const int* dst = ei + NE;

    dim3 egrid((NE + 255) / 256);                 // 3125
    dim3 agrid((NN * 32 + 255) / 256);            // 6250
    dim3 ggrid((NN + RPB - 1) / RPB);             // 1563

    // ---- CSR build (once; shared by both layers) ----
    hipMemsetAsync(deg, 0, (size_t)NN * sizeof(int), stream);
    hipMemsetAsync(cur, 0, (size_t)NN * sizeof(int), stream);
    count_deg<<<egrid, 256, 0, stream>>>(dst, deg);
    scan_deg<<<1, 1024, 0, stream>>>(deg, off);
    scatter_edges<<<egrid, 256, 0, stream>>>(src, dst, ew, off, cur, esrc, ewt);

    // ---- layer 1 ----
    aggregate<<<agrid, 256, 0, stream>>>(x, off, esrc, ewt, We1, be1, agg);
    gemm_add_bias<<<ggrid, 256, 0, stream>>>(x, agg, W1, b1, out, 1);

    // ---- layer 2 ----
    aggregate<<<agrid, 256, 0, stream>>>(out, off, esrc, ewt, We2, be2, agg);
    gemm_add_bias<<<ggrid, 256, 0, stream>>>(out, agg, W2, b2, out, 0);
}

// Round 3
// 376.935 us; speedup vs baseline: 7.5911x; 1.1922x over previous
//
#include <hip/hip_runtime.h>

// GINE 2-layer GNN: N=50000 nodes, E=800000 edges, d=128, f32.
// Round 3: the single-block scan_deg was 76us at 0.14% occupancy (1 CU,
// latency-bound). Replace with 3-stage parallel scan (block_sums ->
// scan_bsums -> write_off), each stage full-grid. Also pack (src,weight)
// into int2 so the CSR scatter is one 8B store/edge and the aggregate
// inner loop is one 8B load/edge.

constexpr int NN = 50000;
constexpr int NE = 800000;
constexpr int D  = 128;
constexpr int RPB = 32;                       // rows per block in the GEMM
constexpr int NBLK = (NN + 255) / 256;        // 196 scan blocks

// ---------------- CSR build ----------------

__global__ __launch_bounds__(256) void count_deg(
    const int* __restrict__ dst, int* __restrict__ deg)
{
    int e = blockIdx.x * 256 + threadIdx.x;
    if (e < NE) atomicAdd(&deg[dst[e]], 1);
}

__global__ __launch_bounds__(256) void block_sums(
    const int* __restrict__ deg, int* __restrict__ bsum)
{
    __shared__ int s[256];
    int t = threadIdx.x;
    int i = blockIdx.x * 256 + t;
    s[t] = (i < NN) ? deg[i] : 0;
    __syncthreads();
    #pragma unroll
    for (int d = 128; d > 0; d >>= 1) {
        if (t < d) s[t] += s[t + d];
        __syncthreads();
    }
    if (t == 0) bsum[blockIdx.x] = s[0];
}

// one block: exclusive scan of bsum[0..NBLK) -> boff
__global__ __launch_bounds__(256) void scan_bsums(
    const int* __restrict__ bsum, int* __restrict__ boff)
{
    __shared__ int s[256];
    int t = threadIdx.x;
    int v = (t < NBLK) ? bsum[t] : 0;
    s[t] = v;
    __syncthreads();
    #pragma unroll
    for (int d = 1; d < 256; d <<= 1) {
        int u = (t >= d) ? s[t - d] : 0;
        __syncthreads();
        s[t] += u;
        __syncthreads();
    }
    if (t < NBLK) boff[t] = s[t] - v;    // exclusive
}

__global__ __launch_bounds__(256) void write_off(
    const int* __restrict__ deg, const int* __restrict__ boff,
    int* __restrict__ off)
{
    __shared__ int s[256];
    int t = threadIdx.x;
    int i = blockIdx.x * 256 + t;
    int v = (i < NN) ? deg[i] : 0;
    s[t] = v;
    __syncthreads();
    #pragma unroll
    for (int d = 1; d < 256; d <<= 1) {
        int u = (t >= d) ? s[t - d] : 0;
        __syncthreads();
        s[t] += u;
        __syncthreads();
    }
    if (i < NN) off[i] = boff[blockIdx.x] + s[t] - v;
    if (blockIdx.x == 0 && t == 0) off[NN] = NE;   // sum of degrees is E
}

__global__ __launch_bounds__(256) void scatter_edges(
    const int*   __restrict__ src,
    const int*   __restrict__ dst,
    const float* __restrict__ ew,
    const int*   __restrict__ off,
    int*         __restrict__ cur,
    int2*        __restrict__ epack)
{
    int e = blockIdx.x * 256 + threadIdx.x;
    if (e >= NE) return;
    int d = dst[e];
    int pos = off[d] + atomicAdd(&cur[d], 1);
    epack[pos] = make_int2(src[e], __float_as_int(ew[e]));
}

// ---------------- per-layer aggregate (gather, no atomics) ----------------

__global__ __launch_bounds__(256) void aggregate(
    const float* __restrict__ h,
    const int*   __restrict__ off,
    const int2*  __restrict__ epack,
    const float* __restrict__ We,
    const float* __restrict__ be,
    float*       __restrict__ agg)
{
    int tid = blockIdx.x * 256 + threadIdx.x;
    int n = tid >> 5;
    if (n >= NN) return;
    int d4 = (tid & 31) << 2;

    float4 wv = *(const float4*)(We + d4);
    float4 bv = *(const float4*)(be + d4);

    int e0 = off[n], e1 = off[n + 1];
    float4 acc = make_float4(0.f, 0.f, 0.f, 0.f);

    int2 p_n = make_int2(0, 0);
    if (e0 < e1) p_n = epack[e0];
    for (int e = e0; e < e1; ) {
        int2 p = p_n;
        ++e;
        if (e < e1) p_n = epack[e];
        float w = __int_as_float(p.y);
        float4 xv = *(const float4*)(h + (size_t)p.x * D + d4);
        acc.x += fmaxf(0.f, xv.x + fmaf(w, wv.x, bv.x));
        acc.y += fmaxf(0.f, xv.y + fmaf(w, wv.y, bv.y));
        acc.z += fmaxf(0.f, xv.z + fmaf(w, wv.z, bv.z));
        acc.w += fmaxf(0.f, xv.w + fmaf(w, wv.w, bv.w));
    }
    *(float4*)(agg + (size_t)n * D + d4) = acc;
}

// ---------------- GEMM: out = (relu?)((A1+A2) @ W + bias) ----------------

__global__ __launch_bounds__(256) void gemm_add_bias(
    const float* __restrict__ A1,
    const float* __restrict__ A2,
    const float* __restrict__ W,
    const float* __restrict__ bias,
    float*       __restrict__ out,
    int relu)
{
    __shared__ float Ws[64 * D];        // half of W at a time: 32 KB
    __shared__ float As[RPB][D + 4];

    const int t    = threadIdx.x;
    const int row0 = blockIdx.x * RPB;

    for (int i = t; i < RPB * (D / 4); i += 256) {
        int r   = i >> 5;
        int c4  = (i & 31) << 2;
        int row = row0 + r;
        float4 v = make_float4(0.f, 0.f, 0.f, 0.f);
        if (row < NN) {
            float4 v1 = *(const float4*)(A1 + (size_t)row * D + c4);
            float4 v2 = *(const float4*)(A2 + (size_t)row * D + c4);
            v = make_float4(v1.x + v2.x, v1.y + v2.y, v1.z + v2.z, v1.w + v2.w);
        }
        *(float4*)&As[r][c4] = v;
    }

    const int tx = t & 31;
    const int ty = t >> 5;
    float acc[4][4] = {};

    for (int half = 0; half < 2; ++half) {
        __syncthreads();
        for (int i = t * 4; i < 64 * D; i += 256 * 4) {
            *(float4*)&Ws[i] = *(const float4*)&W[half * 64 * D + i];
        }
        __syncthreads();

        for (int k0 = 0; k0 < 64; k0 += 4) {
            float4 a[4];
            #pragma unroll
            for (int i = 0; i < 4; ++i)
                a[i] = *(const float4*)&As[ty * 4 + i][half * 64 + k0];

            #pragma unroll
            for (int kk = 0; kk < 4; ++kk) {
                float4 wv = *(const float4*)&Ws[(k0 + kk) * D + tx * 4];
                #pragma unroll
                for (int i = 0; i < 4; ++i) {
                    float av = (kk == 0) ? a[i].x :
                               (kk == 1) ? a[i].y :
                               (kk == 2) ? a[i].z : a[i].w;
                    acc[i][0] = fmaf(av, wv.x, acc[i][0]);
                    acc[i][1] = fmaf(av, wv.y, acc[i][1]);
                    acc[i][2] = fmaf(av, wv.z, acc[i][2]);
                    acc[i][3] = fmaf(av, wv.w, acc[i][3]);
                }
            }
        }
    }

    float4 bv = *(const float4*)(bias + tx * 4);
    #pragma unroll
    for (int i = 0; i < 4; ++i) {
        int row = row0 + ty * 4 + i;
        if (row < NN) {
            float4 o = make_float4(acc[i][0] + bv.x, acc[i][1] + bv.y,
                                   acc[i][2] + bv.z, acc[i][3] + bv.w);
            if (relu) {
                o.x = fmaxf(0.f, o.x); o.y = fmaxf(0.f, o.y);
                o.z = fmaxf(0.f, o.z); o.w = fmaxf(0.f, o.w);
            }
            *(float4*)(out + (size_t)row * D + tx * 4) = o;
        }
    }
}

extern "C" void kernel_launch(void* const* d_in, const int* in_sizes, int n_in,
                              void* d_out, int out_size, void* d_ws, size_t ws_size,
                              hipStream_t stream)
{
    const float* x   = (const float*)d_in[0];
    const int*   ei  = (const int*)  d_in[1];   // [2, E] int32
    const float* ew  = (const float*)d_in[2];   // [E, 1]
    const float* We1 = (const float*)d_in[3];
    const float* be1 = (const float*)d_in[4];
    const float* W1  = (const float*)d_in[5];
    const float* b1  = (const float*)d_in[6];
    const float* We2 = (const float*)d_in[7];
    const float* be2 = (const float*)d_in[8];
    const float* W2  = (const float*)d_in[9];
    const float* b2  = (const float*)d_in[10];

    float* out = (float*)d_out;          // also holds intermediate h

    // workspace layout (ints), epack kept 8B-aligned
    int*   deg   = (int*)d_ws;                   // NN
    int*   bsum  = deg + NN;                     // 256
    int*   boff  = bsum + 256;                   // 256
    int*   off   = boff + 256;                   // NN+2 (pad to even)
    int*   cur   = off + NN + 2;                 // NN
    int2*  epack = (int2*)(cur + NN);            // NE int2 (8B aligned: 150512 ints before)
    float* agg   = (float*)(epack + NE);         // NN*D

    const int* src = ei;
    const int* dst = ei + NE;

    dim3 egrid((NE + 255) / 256);                 // 3125
    dim3 sgrid(NBLK);                             // 196
    dim3 agrid((NN * 32 + 255) / 256);            // 6250
    dim3 ggrid((NN + RPB - 1) / RPB);             // 1563

    // ---- CSR build (once; shared by both layers) ----
    hipMemsetAsync(deg, 0, (size_t)NN * sizeof(int), stream);
    hipMemsetAsync(cur, 0, (size_t)NN * sizeof(int), stream);
    count_deg<<<egrid, 256, 0, stream>>>(dst, deg);
    block_sums<<<sgrid, 256, 0, stream>>>(deg, bsum);
    scan_bsums<<<1, 256, 0, stream>>>(bsum, boff);
    write_off<<<sgrid, 256, 0, stream>>>(deg, boff, off);
    scatter_edges<<<egrid, 256, 0, stream>>>(src, dst, ew, off, cur, epack);

    // ---- layer 1 ----
    aggregate<<<agrid, 256, 0, stream>>>(x, off, epack, We1, be1, agg);
    gemm_add_bias<<<ggrid, 256, 0, stream>>>(x, agg, W1, b1, out, 1);

    // ---- layer 2 ----
    aggregate<<<agrid, 256, 0, stream>>>(out, off, epack, We2, be2, agg);
    gemm_add_bias<<<ggrid, 256, 0, stream>>>(out, agg, W2, b2, out, 0);
}